// Round 1
// baseline (593.272 us; speedup 1.0000x reference)
//
#include <hip/hip_runtime.h>
#include <hip/hip_bf16.h>
#include <math.h>

// Problem constants
#define DM   1024   // d_model
#define NH   16     // heads
#define DKH  64     // d_k per head
#define BB   4      // batch
#define SS   2048   // seq
#define MT   8192   // B*S rows

typedef short bf16x8 __attribute__((ext_vector_type(8)));
typedef float f32x4  __attribute__((ext_vector_type(4)));

__device__ __forceinline__ unsigned short f2bf(float f) {
  union { float f; unsigned u; } a; a.f = f;
  unsigned r = (a.u + 0x7fffu + ((a.u >> 16) & 1u)) >> 16;  // RNE
  return (unsigned short)r;
}

__device__ __forceinline__ void load_lds16(const void* g, void* l) {
  __builtin_amdgcn_global_load_lds(
      (const __attribute__((address_space(1))) void*)g,
      (__attribute__((address_space(3))) void*)l, 16, 0, 0);
}

// ---------------------------------------------------------------------------
// fp32 -> bf16 conversion for 3 activations + 4 weight matrices
// ---------------------------------------------------------------------------
__global__ void cvt_all(const float* __restrict__ q, const float* __restrict__ k,
                        const float* __restrict__ v, const float* __restrict__ wq,
                        const float* __restrict__ wk, const float* __restrict__ wv,
                        const float* __restrict__ wo,
                        unsigned short* __restrict__ xq, unsigned short* __restrict__ xk,
                        unsigned short* __restrict__ xv, unsigned short* __restrict__ uwq,
                        unsigned short* __restrict__ uwk, unsigned short* __restrict__ uwv,
                        unsigned short* __restrict__ uwo) {
  const long NQ = (long)MT * DM / 4;   // float4 count per activation
  const long NW = (long)DM * DM / 4;   // float4 count per weight
  const long total = 3 * NQ + 4 * NW;
  for (long i = (long)blockIdx.x * blockDim.x + threadIdx.x; i < total;
       i += (long)gridDim.x * blockDim.x) {
    const float* s; unsigned short* d; long o;
    if      (i <     NQ)          { s = q;  d = xq;  o = i; }
    else if (i < 2 * NQ)          { s = k;  d = xk;  o = i - NQ; }
    else if (i < 3 * NQ)          { s = v;  d = xv;  o = i - 2 * NQ; }
    else if (i < 3 * NQ + NW)     { s = wq; d = uwq; o = i - 3 * NQ; }
    else if (i < 3 * NQ + 2 * NW) { s = wk; d = uwk; o = i - 3 * NQ - NW; }
    else if (i < 3 * NQ + 3 * NW) { s = wv; d = uwv; o = i - 3 * NQ - 2 * NW; }
    else                          { s = wo; d = uwo; o = i - 3 * NQ - 3 * NW; }
    float4 f = ((const float4*)s)[o];
    ushort4 u;
    u.x = f2bf(f.x); u.y = f2bf(f.y); u.z = f2bf(f.z); u.w = f2bf(f.w);
    ((ushort4*)d)[o] = u;
  }
}

// ---------------------------------------------------------------------------
// Y = X @ W^T + b.  X: [8192][1024] bf16 row-major, W: [1024 out][1024 in] bf16.
// MODE 0: write bf16 head-split [B,NH,S,DKH]. MODE 1: write fp32 [8192][1024].
// 128x128 tile, BK=64, 4 waves (2x2), 16x16x32 bf16 MFMA, global_load_lds(16B).
// ---------------------------------------------------------------------------
template <int MODE>
__global__ __launch_bounds__(256, 2)
void gemm_bt(const unsigned short* __restrict__ X, const unsigned short* __restrict__ Wt,
             const float* __restrict__ bias, void* __restrict__ Y) {
  __shared__ __align__(16) unsigned short Al[128 * 64];
  __shared__ __align__(16) unsigned short Bl[128 * 64];
  const int t = threadIdx.x, lane = t & 63, w = t >> 6;
  const int wr = w >> 1, wc = w & 1;
  const int m0 = blockIdx.y * 128, n0 = blockIdx.x * 128;
  const int lr = lane & 15, lk8 = (lane >> 4) * 8;

  f32x4 acc[4][4] = {};

  for (int kt = 0; kt < 16; ++kt) {
    const int k0 = kt * 64;
#pragma unroll
    for (int p = 0; p < 4; ++p) {
      const int row = (t >> 3) + 32 * p, c8 = (t & 7) * 8;
      load_lds16(X  + (size_t)(m0 + row) * DM + k0 + c8, &Al[row * 64 + c8]);
      load_lds16(Wt + (size_t)(n0 + row) * DM + k0 + c8, &Bl[row * 64 + c8]);
    }
    asm volatile("s_waitcnt vmcnt(0)" ::: "memory");
    __syncthreads();
#pragma unroll
    for (int kk = 0; kk < 2; ++kk) {
      bf16x8 af[4], bfr[4];
#pragma unroll
      for (int m = 0; m < 4; ++m)
        af[m] = *(const bf16x8*)&Al[(64 * wr + 16 * m + lr) * 64 + kk * 32 + lk8];
#pragma unroll
      for (int n = 0; n < 4; ++n)
        bfr[n] = *(const bf16x8*)&Bl[(64 * wc + 16 * n + lr) * 64 + kk * 32 + lk8];
#pragma unroll
      for (int m = 0; m < 4; ++m)
#pragma unroll
        for (int n = 0; n < 4; ++n)
          acc[m][n] = __builtin_amdgcn_mfma_f32_16x16x32_bf16(af[m], bfr[n], acc[m][n], 0, 0, 0);
    }
    __syncthreads();
  }

  // Epilogue. D fragment: col = lane&15, row = (lane>>4)*4 + j  [m89-verified]
#pragma unroll
  for (int m = 0; m < 4; ++m)
#pragma unroll
    for (int n = 0; n < 4; ++n)
#pragma unroll
      for (int j = 0; j < 4; ++j) {
        const int row = m0 + 64 * wr + 16 * m + (lane >> 4) * 4 + j;  // token 0..8191
        const int col = n0 + 64 * wc + 16 * n + lr;                   // feature 0..1023
        const float val = acc[m][n][j] + bias[col];
        if (MODE == 0) {
          const int b = row >> 11, s = row & 2047, h = col >> 6, dk = col & 63;
          ((unsigned short*)Y)[(((size_t)(b * NH + h)) * SS + s) * DKH + dk] = f2bf(val);
        } else {
          ((float*)Y)[(size_t)row * DM + col] = val;
        }
      }
}

// ---------------------------------------------------------------------------
// Flash attention: grid (S/64, B*NH), 256 threads (4 waves x 16 q-rows).
// KBLK = 64 keys per iteration, online softmax, output to Ctx[8192][1024] bf16.
// ---------------------------------------------------------------------------
__global__ __launch_bounds__(256, 2)
void attn(const unsigned short* __restrict__ Qh, const unsigned short* __restrict__ Kh,
          const unsigned short* __restrict__ Vh, unsigned short* __restrict__ Ctx) {
  __shared__ __align__(16) unsigned short Kl[64][72];      // +8 pad: 2-way banks only
  __shared__ __align__(16) unsigned short Vt[64][72];      // V transposed [dk][key]
  __shared__ __align__(16) unsigned short Pl[4][16][72];   // per-wave P staging

  const int t = threadIdx.x, lane = t & 63, w = t >> 6;
  const int lr = lane & 15, lg = lane >> 4, lk8 = lg * 8;
  const int bh = blockIdx.y;
  const int q0 = blockIdx.x * 64;
  const unsigned short* Qp = Qh + (size_t)bh * SS * DKH;
  const unsigned short* Kp = Kh + (size_t)bh * SS * DKH;
  const unsigned short* Vp = Vh + (size_t)bh * SS * DKH;

  // Q fragments held in registers for the whole kernel. A layout: row=lane&15, k=8*(lane>>4)+e
  const unsigned short* qrow = Qp + (size_t)(q0 + 16 * w + lr) * DKH;
  bf16x8 aq0 = *(const bf16x8*)(qrow + lk8);
  bf16x8 aq1 = *(const bf16x8*)(qrow + 32 + lk8);

  f32x4 accO[4] = {};
  float mrun[4], lrun[4];
#pragma unroll
  for (int j = 0; j < 4; ++j) { mrun[j] = -INFINITY; lrun[j] = 0.f; }

  for (int kt = 0; kt < 32; ++kt) {
    __syncthreads();  // previous tile fully consumed
#pragma unroll
    for (int p = 0; p < 2; ++p) {
      const int row = (t >> 3) + 32 * p, c8 = (t & 7) * 8;
      *(bf16x8*)&Kl[row][c8] = *(const bf16x8*)(Kp + (size_t)(kt * 64 + row) * DKH + c8);
      bf16x8 vv = *(const bf16x8*)(Vp + (size_t)(kt * 64 + row) * DKH + c8);
#pragma unroll
      for (int e = 0; e < 8; ++e) Vt[c8 + e][row] = (unsigned short)vv[e];
    }
    __syncthreads();

    // S = Q @ K^T : 16 q-rows x 64 keys per wave
    f32x4 sc[4];
#pragma unroll
    for (int n = 0; n < 4; ++n) {
      bf16x8 b0 = *(const bf16x8*)&Kl[16 * n + lr][lk8];
      bf16x8 b1 = *(const bf16x8*)&Kl[16 * n + lr][32 + lk8];
      f32x4 a = {};
      a = __builtin_amdgcn_mfma_f32_16x16x32_bf16(aq0, b0, a, 0, 0, 0);
      a = __builtin_amdgcn_mfma_f32_16x16x32_bf16(aq1, b1, a, 0, 0, 0);
      sc[n] = a;
    }

    // Online softmax. Row j lives on the 16 lanes sharing (lane>>4).
#pragma unroll
    for (int j = 0; j < 4; ++j) {
      float mm = -INFINITY;
#pragma unroll
      for (int n = 0; n < 4; ++n) { sc[n][j] *= 0.125f; mm = fmaxf(mm, sc[n][j]); }
      mm = fmaxf(mm, __shfl_xor(mm, 1));
      mm = fmaxf(mm, __shfl_xor(mm, 2));
      mm = fmaxf(mm, __shfl_xor(mm, 4));
      mm = fmaxf(mm, __shfl_xor(mm, 8));
      const float mnew  = fmaxf(mrun[j], mm);
      const float alpha = __expf(mrun[j] - mnew);
      float ps = 0.f;
#pragma unroll
      for (int n = 0; n < 4; ++n) {
        const float p = __expf(sc[n][j] - mnew);
        Pl[w][lg * 4 + j][16 * n + lr] = f2bf(p);
        ps += p;
      }
      ps += __shfl_xor(ps, 1);
      ps += __shfl_xor(ps, 2);
      ps += __shfl_xor(ps, 4);
      ps += __shfl_xor(ps, 8);
      lrun[j] = lrun[j] * alpha + ps;
      mrun[j] = mnew;
#pragma unroll
      for (int n2 = 0; n2 < 4; ++n2) accO[n2][j] *= alpha;
    }

    // O += P @ V  (A = P from per-wave LDS, B = V from transposed LDS)
#pragma unroll
    for (int kk = 0; kk < 2; ++kk) {
      bf16x8 ap = *(const bf16x8*)&Pl[w][lr][kk * 32 + lk8];
#pragma unroll
      for (int n2 = 0; n2 < 4; ++n2) {
        bf16x8 bv = *(const bf16x8*)&Vt[16 * n2 + lr][kk * 32 + lk8];
        accO[n2] = __builtin_amdgcn_mfma_f32_16x16x32_bf16(ap, bv, accO[n2], 0, 0, 0);
      }
    }
  }

  // Normalize and write context in [8192][1024] bf16 (token-major, feature = h*64+dk)
  const int b = bh >> 4, h = bh & 15;
#pragma unroll
  for (int n2 = 0; n2 < 4; ++n2)
#pragma unroll
    for (int j = 0; j < 4; ++j) {
      const int token = b * SS + q0 + 16 * w + lg * 4 + j;
      const int col = h * DKH + 16 * n2 + lr;
      Ctx[(size_t)token * DM + col] = f2bf(accO[n2][j] / lrun[j]);
    }
}

// ---------------------------------------------------------------------------
// Launch
// ---------------------------------------------------------------------------
extern "C" void kernel_launch(void* const* d_in, const int* in_sizes, int n_in,
                              void* d_out, int out_size, void* d_ws, size_t ws_size,
                              hipStream_t stream) {
  const float* q  = (const float*)d_in[0];
  const float* k  = (const float*)d_in[1];
  const float* v  = (const float*)d_in[2];
  const float* wq = (const float*)d_in[3];
  const float* bq = (const float*)d_in[4];
  const float* wk = (const float*)d_in[5];
  const float* bk = (const float*)d_in[6];
  const float* wv = (const float*)d_in[7];
  const float* bv = (const float*)d_in[8];
  const float* wo = (const float*)d_in[9];
  const float* bo = (const float*)d_in[10];

  // Workspace layout (bytes). Needs 120 MB total.
  char* ws = (char*)d_ws;
  const size_t ACT = (size_t)MT * DM * 2;   // 16 MB
  const size_t WSZ = (size_t)DM * DM * 2;   //  2 MB
  unsigned short* XQ  = (unsigned short*)(ws);
  unsigned short* XK  = (unsigned short*)(ws + ACT);
  unsigned short* XV  = (unsigned short*)(ws + 2 * ACT);
  unsigned short* WQb = (unsigned short*)(ws + 3 * ACT);
  unsigned short* WKb = (unsigned short*)(ws + 3 * ACT + WSZ);
  unsigned short* WVb = (unsigned short*)(ws + 3 * ACT + 2 * WSZ);
  unsigned short* WOb = (unsigned short*)(ws + 3 * ACT + 3 * WSZ);
  unsigned short* QH  = (unsigned short*)(ws + 3 * ACT + 4 * WSZ);
  unsigned short* KH  = (unsigned short*)(ws + 4 * ACT + 4 * WSZ);
  unsigned short* VH  = (unsigned short*)(ws + 5 * ACT + 4 * WSZ);
  unsigned short* CTX = (unsigned short*)(ws + 6 * ACT + 4 * WSZ);

  cvt_all<<<dim3(2048), dim3(256), 0, stream>>>(q, k, v, wq, wk, wv, wo,
                                                XQ, XK, XV, WQb, WKb, WVb, WOb);

  const dim3 gg(DM / 128, MT / 128, 1);  // (8, 64)
  gemm_bt<0><<<gg, 256, 0, stream>>>(XQ, WQb, bq, QH);
  gemm_bt<0><<<gg, 256, 0, stream>>>(XK, WKb, bk, KH);
  gemm_bt<0><<<gg, 256, 0, stream>>>(XV, WVb, bv, VH);

  attn<<<dim3(SS / 64, BB * NH), 256, 0, stream>>>(QH, KH, VH, CTX);

  gemm_bt<1><<<gg, 256, 0, stream>>>(CTX, WOb, bo, (float*)d_out);
}

// Round 3
// 527.038 us; speedup vs baseline: 1.1257x; 1.1257x over previous
//
#include <hip/hip_runtime.h>
#include <hip/hip_bf16.h>
#include <math.h>

// Problem constants
#define DM   1024   // d_model
#define NH   16     // heads
#define DKH  64     // d_k per head
#define BB   4      // batch
#define SS   2048   // seq
#define MT   8192   // B*S rows

// 0.125 * log2(e): folds score scale AND exp->exp2 conversion into Q projection
#define QSCALE 0.18033688011112042f

typedef short bf16x8 __attribute__((ext_vector_type(8)));
typedef float f32x4  __attribute__((ext_vector_type(4)));

__device__ __forceinline__ unsigned short f2bf(float f) {
  union { float f; unsigned u; } a; a.f = f;
  unsigned r = (a.u + 0x7fffu + ((a.u >> 16) & 1u)) >> 16;  // RNE
  return (unsigned short)r;
}

__device__ __forceinline__ void load_lds16(const void* g, void* l) {
  __builtin_amdgcn_global_load_lds(
      (const __attribute__((address_space(1))) void*)g,
      (__attribute__((address_space(3))) void*)l, 16, 0, 0);
}

// ---------------------------------------------------------------------------
// fp32 -> bf16 conversion for 3 activations + 4 weight matrices
// ---------------------------------------------------------------------------
__global__ void cvt_all(const float* __restrict__ q, const float* __restrict__ k,
                        const float* __restrict__ v, const float* __restrict__ wq,
                        const float* __restrict__ wk, const float* __restrict__ wv,
                        const float* __restrict__ wo,
                        unsigned short* __restrict__ xq, unsigned short* __restrict__ xk,
                        unsigned short* __restrict__ xv, unsigned short* __restrict__ uwq,
                        unsigned short* __restrict__ uwk, unsigned short* __restrict__ uwv,
                        unsigned short* __restrict__ uwo) {
  const long NQ = (long)MT * DM / 4;   // float4 count per activation
  const long NW = (long)DM * DM / 4;   // float4 count per weight
  const long total = 3 * NQ + 4 * NW;
  for (long i = (long)blockIdx.x * blockDim.x + threadIdx.x; i < total;
       i += (long)gridDim.x * blockDim.x) {
    const float* s; unsigned short* d; long o;
    if      (i <     NQ)          { s = q;  d = xq;  o = i; }
    else if (i < 2 * NQ)          { s = k;  d = xk;  o = i - NQ; }
    else if (i < 3 * NQ)          { s = v;  d = xv;  o = i - 2 * NQ; }
    else if (i < 3 * NQ + NW)     { s = wq; d = uwq; o = i - 3 * NQ; }
    else if (i < 3 * NQ + 2 * NW) { s = wk; d = uwk; o = i - 3 * NQ - NW; }
    else if (i < 3 * NQ + 3 * NW) { s = wv; d = uwv; o = i - 3 * NQ - 2 * NW; }
    else                          { s = wo; d = uwo; o = i - 3 * NQ - 3 * NW; }
    float4 f = ((const float4*)s)[o];
    ushort4 u;
    u.x = f2bf(f.x); u.y = f2bf(f.y); u.z = f2bf(f.z); u.w = f2bf(f.w);
    ((ushort4*)d)[o] = u;
  }
}

// ---------------------------------------------------------------------------
// Y = (X @ W^T + b) * oscale.  X: [8192][1024] bf16, W: [1024 out][1024 in] bf16.
// MODE 0: write bf16 head-split [B,NH,S,DKH]. MODE 1: write fp32 [8192][1024].
// ---------------------------------------------------------------------------
template <int MODE>
__global__ __launch_bounds__(256, 2)
void gemm_bt(const unsigned short* __restrict__ X, const unsigned short* __restrict__ Wt,
             const float* __restrict__ bias, float oscale, void* __restrict__ Y) {
  __shared__ __align__(16) unsigned short Al[128 * 64];
  __shared__ __align__(16) unsigned short Bl[128 * 64];
  const int t = threadIdx.x, lane = t & 63, w = t >> 6;
  const int wr = w >> 1, wc = w & 1;
  const int m0 = blockIdx.y * 128, n0 = blockIdx.x * 128;
  const int lr = lane & 15, lk8 = (lane >> 4) * 8;

  f32x4 acc[4][4] = {};

  for (int kt = 0; kt < 16; ++kt) {
    const int k0 = kt * 64;
#pragma unroll
    for (int p = 0; p < 4; ++p) {
      const int row = (t >> 3) + 32 * p, c8 = (t & 7) * 8;
      load_lds16(X  + (size_t)(m0 + row) * DM + k0 + c8, &Al[row * 64 + c8]);
      load_lds16(Wt + (size_t)(n0 + row) * DM + k0 + c8, &Bl[row * 64 + c8]);
    }
    asm volatile("s_waitcnt vmcnt(0)" ::: "memory");
    __syncthreads();
#pragma unroll
    for (int kk = 0; kk < 2; ++kk) {
      bf16x8 af[4], bfr[4];
#pragma unroll
      for (int m = 0; m < 4; ++m)
        af[m] = *(const bf16x8*)&Al[(64 * wr + 16 * m + lr) * 64 + kk * 32 + lk8];
#pragma unroll
      for (int n = 0; n < 4; ++n)
        bfr[n] = *(const bf16x8*)&Bl[(64 * wc + 16 * n + lr) * 64 + kk * 32 + lk8];
#pragma unroll
      for (int m = 0; m < 4; ++m)
#pragma unroll
        for (int n = 0; n < 4; ++n)
          acc[m][n] = __builtin_amdgcn_mfma_f32_16x16x32_bf16(af[m], bfr[n], acc[m][n], 0, 0, 0);
    }
    __syncthreads();
  }

#pragma unroll
  for (int m = 0; m < 4; ++m)
#pragma unroll
    for (int n = 0; n < 4; ++n)
#pragma unroll
      for (int j = 0; j < 4; ++j) {
        const int row = m0 + 64 * wr + 16 * m + (lane >> 4) * 4 + j;  // token
        const int col = n0 + 64 * wc + 16 * n + lr;                   // feature
        const float val = (acc[m][n][j] + bias[col]) * oscale;
        if (MODE == 0) {
          const int b = row >> 11, s = row & 2047, h = col >> 6, dk = col & 63;
          ((unsigned short*)Y)[(((size_t)(b * NH + h)) * SS + s) * DKH + dk] = f2bf(val);
        } else {
          ((float*)Y)[(size_t)row * DM + col] = val;
        }
      }
}

// ---------------------------------------------------------------------------
// VH [bh][s][dk] -> VT [bh][dk][s]  (64x64 tiles through LDS)
// ---------------------------------------------------------------------------
__global__ __launch_bounds__(256)
void transposeV(const unsigned short* __restrict__ VH, unsigned short* __restrict__ VTg) {
  __shared__ unsigned short T[64][66];   // odd-ish stride: conflict-light both sides
  const int t = threadIdx.x;
  const int bh = blockIdx.y, s0 = blockIdx.x * 64;
  const unsigned short* src = VH + ((size_t)bh * SS + s0) * DKH;
#pragma unroll
  for (int p = 0; p < 2; ++p) {
    const int c = p * 256 + t, row = c >> 3, c8 = (c & 7) * 8;
    bf16x8 v = *(const bf16x8*)(src + (size_t)row * DKH + c8);
#pragma unroll
    for (int e = 0; e < 8; ++e) T[row][c8 + e] = (unsigned short)v[e];
  }
  __syncthreads();
#pragma unroll
  for (int p = 0; p < 2; ++p) {
    const int c = p * 256 + t, dk = c >> 3, s8 = (c & 7) * 8;
    bf16x8 v;
#pragma unroll
    for (int e = 0; e < 8; ++e) v[e] = (short)T[s8 + e][dk];
    *(bf16x8*)(VTg + ((size_t)bh * DKH + dk) * SS + s0 + s8) = v;
  }
}

// ---------------------------------------------------------------------------
// Flash attention. grid (S/128, B*NH), 256 thr = 4 waves x 32 q-rows.
// K tile [64 key][64 dk], V^T tile [64 dk][64 key]: both staged with
// global_load_lds(16B) into linear LDS, XOR-swizzled (byte ^= (row&7)<<4)
// via pre-swizzled global source.  Double-buffered (2-phase).
// Scores arrive already in exp2 domain (QSCALE folded into Q projection).
// ---------------------------------------------------------------------------
__global__ __launch_bounds__(256, 3)
void attn(const unsigned short* __restrict__ Qh, const unsigned short* __restrict__ Kh,
          const unsigned short* __restrict__ VTg, unsigned short* __restrict__ Ctx) {
  __shared__ __align__(16) unsigned short Kl[2][64 * 64];
  __shared__ __align__(16) unsigned short Vl[2][64 * 64];
  __shared__ __align__(16) unsigned short Pl[4][32 * 64];

  const int t = threadIdx.x, lane = t & 63, w = t >> 6;
  const int lr = lane & 15, lg = lane >> 4;
  const int bh = blockIdx.y;
  const int q0 = blockIdx.x * 128;
  const unsigned short* Qp = Qh + (size_t)bh * SS * DKH;
  const unsigned short* Kp = Kh + (size_t)bh * SS * DKH;
  const unsigned short* Vp = VTg + (size_t)bh * DKH * SS;   // [dk][s]

  // Q fragments in registers. A layout: row = lane&15, k = 8*(lane>>4)+e
  bf16x8 aq[2][2];
#pragma unroll
  for (int m = 0; m < 2; ++m) {
    const unsigned short* qr = Qp + (size_t)(q0 + 32 * w + 16 * m + lr) * DKH + lg * 8;
    aq[m][0] = *(const bf16x8*)qr;
    aq[m][1] = *(const bf16x8*)(qr + 32);
  }

  f32x4 accO[2][4] = {};
  float mrun[2][4], lrun[2][4];
#pragma unroll
  for (int m = 0; m < 2; ++m)
#pragma unroll
    for (int j = 0; j < 4; ++j) { mrun[m][j] = -INFINITY; lrun[m][j] = 0.f; }

  // Staging chunk decode (constant per thread): chunk c covers LDS bytes [16c,16c+16)
  // LDS row = c>>3 (128B rows), LDS 16B-slot = c&7; global slot = slot ^ (row&7).
  int srow[2], scol[2];
#pragma unroll
  for (int p = 0; p < 2; ++p) {
    const int c = p * 256 + t;
    srow[p] = c >> 3;
    scol[p] = (((c & 7) * 16) ^ ((srow[p] & 7) << 4)) >> 1;   // shorts
  }

#define STAGE(kt_, buf_)                                                          \
  {                                                                               \
    _Pragma("unroll")                                                             \
    for (int p = 0; p < 2; ++p) {                                                 \
      const int c = p * 256 + t;                                                  \
      load_lds16(Kp + (size_t)((kt_) * 64 + srow[p]) * DKH + scol[p],             \
                 &Kl[buf_][c * 8]);                                               \
      load_lds16(Vp + (size_t)srow[p] * SS + (kt_) * 64 + scol[p],                \
                 &Vl[buf_][c * 8]);                                               \
    }                                                                             \
  }

  STAGE(0, 0);
  asm volatile("s_waitcnt vmcnt(0)" ::: "memory");
  __syncthreads();

  // Precomputed swizzled read offsets (shorts). col bytes = 64*kk + 16*lg.
  int boff[4][2], aoff[2][2];
#pragma unroll
  for (int n = 0; n < 4; ++n)
#pragma unroll
    for (int kk = 0; kk < 2; ++kk)
      boff[n][kk] = ((16 * n + lr) * 128 + ((64 * kk + 16 * lg) ^ ((lr & 7) << 4))) >> 1;
#pragma unroll
  for (int m = 0; m < 2; ++m)
#pragma unroll
    for (int kk = 0; kk < 2; ++kk)
      aoff[m][kk] = ((16 * m + lr) * 128 + ((64 * kk + 16 * lg) ^ ((lr & 7) << 4))) >> 1;

  for (int kt = 0; kt < 32; ++kt) {
    const int buf = kt & 1;
    if (kt + 1 < 32) STAGE(kt + 1, buf ^ 1);

    const unsigned short* Kb = Kl[buf];
    const unsigned short* Vb = Vl[buf];
    unsigned short* Pw = Pl[w];

#pragma unroll
    for (int m = 0; m < 2; ++m) {
      // S-tile = Q @ K^T (already in exp2 domain)
      f32x4 sc[4];
#pragma unroll
      for (int n = 0; n < 4; ++n) {
        bf16x8 b0 = *(const bf16x8*)&Kb[boff[n][0]];
        bf16x8 b1 = *(const bf16x8*)&Kb[boff[n][1]];
        f32x4 z = {};
        z = __builtin_amdgcn_mfma_f32_16x16x32_bf16(aq[m][0], b0, z, 0, 0, 0);
        z = __builtin_amdgcn_mfma_f32_16x16x32_bf16(aq[m][1], b1, z, 0, 0, 0);
        sc[n] = z;
      }
      // Online softmax per q-row (row = 16m + 4*lg + j; 16 lanes share a row)
#pragma unroll
      for (int j = 0; j < 4; ++j) {
        float mm = fmaxf(fmaxf(sc[0][j], sc[1][j]), fmaxf(sc[2][j], sc[3][j]));
        mm = fmaxf(mm, __shfl_xor(mm, 1));
        mm = fmaxf(mm, __shfl_xor(mm, 2));
        mm = fmaxf(mm, __shfl_xor(mm, 4));
        mm = fmaxf(mm, __shfl_xor(mm, 8));
        const float mnew  = fmaxf(mrun[m][j], mm);
        const float alpha = __builtin_amdgcn_exp2f(mrun[m][j] - mnew);
        const int prow = 16 * m + 4 * lg + j;
        const int rsw  = (prow & 7) << 4;
        float ps = 0.f;
#pragma unroll
        for (int n = 0; n < 4; ++n) {
          const float p = __builtin_amdgcn_exp2f(sc[n][j] - mnew);
          ps += p;
          Pw[(prow * 128 + ((32 * n + 2 * lr) ^ rsw)) >> 1] = f2bf(p);
        }
        ps += __shfl_xor(ps, 1);
        ps += __shfl_xor(ps, 2);
        ps += __shfl_xor(ps, 4);
        ps += __shfl_xor(ps, 8);
        lrun[m][j] = lrun[m][j] * alpha + ps;
        mrun[m][j] = mnew;
#pragma unroll
        for (int n2 = 0; n2 < 4; ++n2) accO[m][n2][j] *= alpha;
      }
    }

    // O += P @ V   (A = P from Pl, B = V^T rows from Vl; both swizzled)
#pragma unroll
    for (int kk = 0; kk < 2; ++kk) {
      bf16x8 bv[4];
#pragma unroll
      for (int n2 = 0; n2 < 4; ++n2) bv[n2] = *(const bf16x8*)&Vb[boff[n2][kk]];
#pragma unroll
      for (int m = 0; m < 2; ++m) {
        bf16x8 ap = *(const bf16x8*)&Pw[aoff[m][kk]];
#pragma unroll
        for (int n2 = 0; n2 < 4; ++n2)
          accO[m][n2] = __builtin_amdgcn_mfma_f32_16x16x32_bf16(ap, bv[n2], accO[m][n2], 0, 0, 0);
      }
    }

    asm volatile("s_waitcnt vmcnt(0)" ::: "memory");
    __syncthreads();
  }

  // Write context [8192][1024] bf16 (token-major, feature = h*64 + dk)
  const int b = bh >> 4, h = bh & 15;
#pragma unroll
  for (int m = 0; m < 2; ++m)
#pragma unroll
    for (int j = 0; j < 4; ++j) {
      const float inv = 1.f / lrun[m][j];
      const int token = b * SS + q0 + 32 * w + 16 * m + 4 * lg + j;
#pragma unroll
      for (int n2 = 0; n2 < 4; ++n2)
        Ctx[(size_t)token * DM + h * DKH + 16 * n2 + lr] = f2bf(accO[m][n2][j] * inv);
    }
}

// ---------------------------------------------------------------------------
// Launch
// ---------------------------------------------------------------------------
extern "C" void kernel_launch(void* const* d_in, const int* in_sizes, int n_in,
                              void* d_out, int out_size, void* d_ws, size_t ws_size,
                              hipStream_t stream) {
  const float* q  = (const float*)d_in[0];
  const float* k  = (const float*)d_in[1];
  const float* v  = (const float*)d_in[2];
  const float* wq = (const float*)d_in[3];
  const float* bq = (const float*)d_in[4];
  const float* wk = (const float*)d_in[5];
  const float* bk = (const float*)d_in[6];
  const float* wv = (const float*)d_in[7];
  const float* bv = (const float*)d_in[8];
  const float* wo = (const float*)d_in[9];
  const float* bo = (const float*)d_in[10];

  // Workspace layout (120 MB). VT aliases XQ (dead after the Q projection).
  char* ws = (char*)d_ws;
  const size_t ACT = (size_t)MT * DM * 2;   // 16 MB
  const size_t WSZ = (size_t)DM * DM * 2;   //  2 MB
  unsigned short* XQ  = (unsigned short*)(ws);
  unsigned short* XK  = (unsigned short*)(ws + ACT);
  unsigned short* XV  = (unsigned short*)(ws + 2 * ACT);
  unsigned short* WQb = (unsigned short*)(ws + 3 * ACT);
  unsigned short* WKb = (unsigned short*)(ws + 3 * ACT + WSZ);
  unsigned short* WVb = (unsigned short*)(ws + 3 * ACT + 2 * WSZ);
  unsigned short* WOb = (unsigned short*)(ws + 3 * ACT + 3 * WSZ);
  unsigned short* QH  = (unsigned short*)(ws + 3 * ACT + 4 * WSZ);
  unsigned short* KH  = (unsigned short*)(ws + 4 * ACT + 4 * WSZ);
  unsigned short* VH  = (unsigned short*)(ws + 5 * ACT + 4 * WSZ);
  unsigned short* CTX = (unsigned short*)(ws + 6 * ACT + 4 * WSZ);
  unsigned short* VT  = XQ;   // reuse

  cvt_all<<<dim3(2048), dim3(256), 0, stream>>>(q, k, v, wq, wk, wv, wo,
                                                XQ, XK, XV, WQb, WKb, WVb, WOb);

  const dim3 gg(DM / 128, MT / 128, 1);  // (8, 64)
  gemm_bt<0><<<gg, 256, 0, stream>>>(XQ, WQb, bq, QSCALE, QH);
  gemm_bt<0><<<gg, 256, 0, stream>>>(XK, WKb, bk, 1.0f, KH);
  gemm_bt<0><<<gg, 256, 0, stream>>>(XV, WVb, bv, 1.0f, VH);

  transposeV<<<dim3(SS / 64, BB * NH), 256, 0, stream>>>(VH, VT);

  attn<<<dim3(SS / 128, BB * NH), 256, 0, stream>>>(QH, KH, VT, CTX);

  gemm_bt<1><<<gg, 256, 0, stream>>>(CTX, WOb, bo, 1.0f, (float*)d_out);
}

// Round 5
// 382.631 us; speedup vs baseline: 1.5505x; 1.3774x over previous
//
#include <hip/hip_runtime.h>
#include <hip/hip_bf16.h>
#include <math.h>

// Problem constants
#define DM   1024   // d_model
#define NH   16     // heads
#define DKH  64     // d_k per head
#define BB   4      // batch
#define SS   2048   // seq
#define MT   8192   // B*S rows

// 0.125 * log2(e): folds score scale AND exp->exp2 conversion into Q projection
#define QSCALE 0.18033688011112042f

typedef short bf16x8 __attribute__((ext_vector_type(8)));
typedef float f32x4  __attribute__((ext_vector_type(4)));
typedef float f32x16 __attribute__((ext_vector_type(16)));

__device__ __forceinline__ unsigned short f2bf(float f) {
  union { float f; unsigned u; } a; a.f = f;
  unsigned r = (a.u + 0x7fffu + ((a.u >> 16) & 1u)) >> 16;  // RNE
  return (unsigned short)r;
}

__device__ __forceinline__ void load_lds16(const void* g, void* l) {
  __builtin_amdgcn_global_load_lds(
      (const __attribute__((address_space(1))) void*)g,
      (__attribute__((address_space(3))) void*)l, 16, 0, 0);
}

// ---------------------------------------------------------------------------
// fp32 -> bf16 conversion for 3 activations + 4 weight matrices
// ---------------------------------------------------------------------------
__global__ void cvt_all(const float* __restrict__ q, const float* __restrict__ k,
                        const float* __restrict__ v, const float* __restrict__ wq,
                        const float* __restrict__ wk, const float* __restrict__ wv,
                        const float* __restrict__ wo,
                        unsigned short* __restrict__ xq, unsigned short* __restrict__ xk,
                        unsigned short* __restrict__ xv, unsigned short* __restrict__ uwq,
                        unsigned short* __restrict__ uwk, unsigned short* __restrict__ uwv,
                        unsigned short* __restrict__ uwo) {
  const long NQ = (long)MT * DM / 4;   // float4 count per activation
  const long NW = (long)DM * DM / 4;   // float4 count per weight
  const long total = 3 * NQ + 4 * NW;
  for (long i = (long)blockIdx.x * blockDim.x + threadIdx.x; i < total;
       i += (long)gridDim.x * blockDim.x) {
    const float* s; unsigned short* d; long o;
    if      (i <     NQ)          { s = q;  d = xq;  o = i; }
    else if (i < 2 * NQ)          { s = k;  d = xk;  o = i - NQ; }
    else if (i < 3 * NQ)          { s = v;  d = xv;  o = i - 2 * NQ; }
    else if (i < 3 * NQ + NW)     { s = wq; d = uwq; o = i - 3 * NQ; }
    else if (i < 3 * NQ + 2 * NW) { s = wk; d = uwk; o = i - 3 * NQ - NW; }
    else if (i < 3 * NQ + 3 * NW) { s = wv; d = uwv; o = i - 3 * NQ - 2 * NW; }
    else                          { s = wo; d = uwo; o = i - 3 * NQ - 3 * NW; }
    float4 f = ((const float4*)s)[o];
    ushort4 u;
    u.x = f2bf(f.x); u.y = f2bf(f.y); u.z = f2bf(f.z); u.w = f2bf(f.w);
    ((ushort4*)d)[o] = u;
  }
}

// ---------------------------------------------------------------------------
// Y = (X @ W^T + b) * oscale.  X: [8192][1024] bf16, W: [1024 out][1024 in] bf16.
// MODE 0: write bf16 head-split [B,NH,S,DKH]. MODE 1: write fp32 [8192][1024].
// ---------------------------------------------------------------------------
template <int MODE>
__global__ __launch_bounds__(256, 2)
void gemm_bt(const unsigned short* __restrict__ X, const unsigned short* __restrict__ Wt,
             const float* __restrict__ bias, float oscale, void* __restrict__ Y) {
  __shared__ __align__(16) unsigned short Al[128 * 64];
  __shared__ __align__(16) unsigned short Bl[128 * 64];
  const int t = threadIdx.x, lane = t & 63, w = t >> 6;
  const int wr = w >> 1, wc = w & 1;
  const int m0 = blockIdx.y * 128, n0 = blockIdx.x * 128;
  const int lr = lane & 15, lk8 = (lane >> 4) * 8;

  f32x4 acc[4][4] = {};

  for (int kt = 0; kt < 16; ++kt) {
    const int k0 = kt * 64;
#pragma unroll
    for (int p = 0; p < 4; ++p) {
      const int row = (t >> 3) + 32 * p, c8 = (t & 7) * 8;
      load_lds16(X  + (size_t)(m0 + row) * DM + k0 + c8, &Al[row * 64 + c8]);
      load_lds16(Wt + (size_t)(n0 + row) * DM + k0 + c8, &Bl[row * 64 + c8]);
    }
    asm volatile("s_waitcnt vmcnt(0)" ::: "memory");
    __syncthreads();
#pragma unroll
    for (int kk = 0; kk < 2; ++kk) {
      bf16x8 af[4], bfr[4];
#pragma unroll
      for (int m = 0; m < 4; ++m)
        af[m] = *(const bf16x8*)&Al[(64 * wr + 16 * m + lr) * 64 + kk * 32 + lk8];
#pragma unroll
      for (int n = 0; n < 4; ++n)
        bfr[n] = *(const bf16x8*)&Bl[(64 * wc + 16 * n + lr) * 64 + kk * 32 + lk8];
#pragma unroll
      for (int m = 0; m < 4; ++m)
#pragma unroll
        for (int n = 0; n < 4; ++n)
          acc[m][n] = __builtin_amdgcn_mfma_f32_16x16x32_bf16(af[m], bfr[n], acc[m][n], 0, 0, 0);
    }
    __syncthreads();
  }

#pragma unroll
  for (int m = 0; m < 4; ++m)
#pragma unroll
    for (int n = 0; n < 4; ++n)
#pragma unroll
      for (int j = 0; j < 4; ++j) {
        const int row = m0 + 64 * wr + 16 * m + (lane >> 4) * 4 + j;  // token
        const int col = n0 + 64 * wc + 16 * n + lr;                   // feature
        const float val = (acc[m][n][j] + bias[col]) * oscale;
        if (MODE == 0) {
          const int b = row >> 11, s = row & 2047, h = col >> 6, dk = col & 63;
          ((unsigned short*)Y)[(((size_t)(b * NH + h)) * SS + s) * DKH + dk] = f2bf(val);
        } else {
          ((float*)Y)[(size_t)row * DM + col] = val;
        }
      }
}

// ---------------------------------------------------------------------------
// VH [bh][s][dk] -> VT [bh][dk][s]  (64x64 tiles through LDS)
// ---------------------------------------------------------------------------
__global__ __launch_bounds__(256)
void transposeV(const unsigned short* __restrict__ VH, unsigned short* __restrict__ VTg) {
  __shared__ unsigned short T[64][66];
  const int t = threadIdx.x;
  const int bh = blockIdx.y, s0 = blockIdx.x * 64;
  const unsigned short* src = VH + ((size_t)bh * SS + s0) * DKH;
#pragma unroll
  for (int p = 0; p < 2; ++p) {
    const int c = p * 256 + t, row = c >> 3, c8 = (c & 7) * 8;
    bf16x8 v = *(const bf16x8*)(src + (size_t)row * DKH + c8);
#pragma unroll
    for (int e = 0; e < 8; ++e) T[row][c8 + e] = (unsigned short)v[e];
  }
  __syncthreads();
#pragma unroll
  for (int p = 0; p < 2; ++p) {
    const int c = p * 256 + t, dk = c >> 3, s8 = (c & 7) * 8;
    bf16x8 v;
#pragma unroll
    for (int e = 0; e < 8; ++e) v[e] = (short)T[s8 + e][dk];
    *(bf16x8*)(VTg + ((size_t)bh * DKH + dk) * SS + s0 + s8) = v;
  }
}

// ---------------------------------------------------------------------------
// Flash attention, swapped-QK^T 32x32 structure (T12/m214 port, D=64).
// grid (S/256, B*NH), 512 thr = 8 waves x 32 q-rows.
// mfma_32x32x16(K, Q): D col = lane&31 = q-row -> P row is lane-local.
// Softmax: in-lane trees + __shfl_xor(,32) cross-half combine
// (NOT asm permlane with equal operands -- register-coalescing hazard was
//  the R4 bug: v_permlane32_swap v0,v0 degenerates to a half-swap and the
//  row max/sum collapse to the partner half only).
// P -> PV A-frags via v_cvt_pk_bf16_f32 + __builtin_amdgcn_permlane32_swap
// (distinct operands; builtin returns both results as separate values).
// Defer-max (T13, THR=8): accO rescale (16 bpermutes) only on violation.
// K [64k][64d], V^T [64dk][64s] tiles: global_load_lds(16B), XOR-swizzled,
// double-buffered.  Scores arrive in exp2 domain (QSCALE folded into Q).
// ---------------------------------------------------------------------------
__global__ __launch_bounds__(512, 4)
void attn(const unsigned short* __restrict__ Qh, const unsigned short* __restrict__ Kh,
          const unsigned short* __restrict__ VTg, unsigned short* __restrict__ Ctx) {
  __shared__ __align__(16) unsigned short Kl[2][4096];   // [64 key][64 dk] swizzled
  __shared__ __align__(16) unsigned short Vl[2][4096];   // [64 dk][64 key] swizzled

  const int t = threadIdx.x, lane = t & 63, w = t >> 6;
  const int lr32 = lane & 31, hi = lane >> 5;
  const int bh = blockIdx.y;
  const int q0 = blockIdx.x * 256;
  const unsigned short* Qp = Qh + (size_t)bh * SS * DKH;
  const unsigned short* Kp = Kh + (size_t)bh * SS * DKH;
  const unsigned short* Vp = VTg + (size_t)bh * DKH * SS;   // [dk][s]

  // Q B-frags (row = lane&31 = qrow, k = 8*hi+e), d = 16*ks + 8*hi + e
  const int qrow = q0 + w * 32 + lr32;
  bf16x8 qB[4];
#pragma unroll
  for (int ks = 0; ks < 4; ++ks)
    qB[ks] = *(const bf16x8*)(Qp + (size_t)qrow * DKH + 16 * ks + 8 * hi);

  f32x16 accO[2] = {};
  float m = -INFINITY, l = 0.f;

  // Staging: 512 chunks of 16B per tile; chunk c=t: LDS row c>>3, slot c&7,
  // global col pre-swizzled so read-side XOR matches (rule #21).
  const int srow = t >> 3;
  const int scol = (((t & 7) * 16) ^ ((srow & 7) << 4)) >> 1;   // shorts

#define STAGE(kt_, buf_)                                                      \
  {                                                                           \
    load_lds16(Kp + (size_t)((kt_) * 64 + srow) * DKH + scol,                 \
               &Kl[buf_][t * 8]);                                             \
    load_lds16(Vp + (size_t)srow * SS + (kt_) * 64 + scol,                    \
               &Vl[buf_][t * 8]);                                             \
  }

  STAGE(0, 0);
  asm volatile("s_waitcnt vmcnt(0)" ::: "memory");
  __syncthreads();

  // Swizzled byte offsets within an 8KB tile: row' = lr32 (+32*blk via +4096),
  // col bytes = 32*j + 16*hi, XORed with (row&7)<<4.  Same table serves K & V.
  const int rsw = (lr32 & 7) << 4;
  int obase[4];
#pragma unroll
  for (int j = 0; j < 4; ++j)
    obase[j] = lr32 * 128 + ((32 * j + 16 * hi) ^ rsw);

  for (int kt = 0; kt < 32; ++kt) {
    const int buf = kt & 1;
    if (kt + 1 < 32) STAGE(kt + 1, buf ^ 1);

    const char* Kbase = (const char*)&Kl[buf][0];
    const char* Vbase = (const char*)&Vl[buf][0];

#pragma unroll
    for (int kb = 0; kb < 2; ++kb) {
      // ---- QK^T (swapped): s[r] = S[key = 32*kb + rho(r,hi)][qrow] ----
      f32x16 s = {};
      __builtin_amdgcn_s_setprio(1);
#pragma unroll
      for (int ks = 0; ks < 4; ++ks) {
        bf16x8 ka = *(const bf16x8*)(Kbase + kb * 4096 + obase[ks]);
        s = __builtin_amdgcn_mfma_f32_32x32x16_bf16(ka, qB[ks], s, 0, 0, 0);
      }
      __builtin_amdgcn_s_setprio(0);

      // ---- row max: in-lane tree + cross-half combine (shfl_xor 32) ----
      float m0 = fmaxf(fmaxf(s[0], s[1]), fmaxf(s[2], s[3]));
      float m1 = fmaxf(fmaxf(s[4], s[5]), fmaxf(s[6], s[7]));
      float m2 = fmaxf(fmaxf(s[8], s[9]), fmaxf(s[10], s[11]));
      float m3 = fmaxf(fmaxf(s[12], s[13]), fmaxf(s[14], s[15]));
      float pmax = fmaxf(fmaxf(m0, m1), fmaxf(m2, m3));
      pmax = fmaxf(pmax, __shfl_xor(pmax, 32));

      // ---- defer-max (T13): rescale only when max grows past THR=8 ----
      if (!__all(pmax - m <= 8.0f)) {
        const float mnew = fmaxf(m, pmax);
        const float al = __builtin_amdgcn_exp2f(m - mnew);
        l *= al;
        const int abase = hi * 16;   // addr 4*rho = 4*((r&3)+8*(r>>2)) + 16*hi
#pragma unroll
        for (int r = 0; r < 16; ++r) {
          const int rho4 = ((r & 3) + 8 * (r >> 2)) * 4;
          const float ar = __int_as_float(
              __builtin_amdgcn_ds_bpermute(abase + rho4, __float_as_int(al)));
          accO[0][r] *= ar;
          accO[1][r] *= ar;
        }
        m = mnew;
      }

      // ---- P = exp2(s - m), row sum ----
#pragma unroll
      for (int r = 0; r < 16; ++r) s[r] = __builtin_amdgcn_exp2f(s[r] - m);
      float s0 = (s[0] + s[1]) + (s[2] + s[3]);
      float s1 = (s[4] + s[5]) + (s[6] + s[7]);
      float s2 = (s[8] + s[9]) + (s[10] + s[11]);
      float s3 = (s[12] + s[13]) + (s[14] + s[15]);
      float ps = (s0 + s1) + (s2 + s3);
      ps += __shfl_xor(ps, 32);
      l += ps;

      // ---- pack P to bf16 pair-words (W[2g+w] = group g word w) ----
      unsigned W[8];
#pragma unroll
      for (int g = 0; g < 4; ++g) {
        asm("v_cvt_pk_bf16_f32 %0, %1, %2" : "=v"(W[2 * g])     : "v"(s[4 * g]),     "v"(s[4 * g + 1]));
        asm("v_cvt_pk_bf16_f32 %0, %1, %2" : "=v"(W[2 * g + 1]) : "v"(s[4 * g + 2]), "v"(s[4 * g + 3]));
      }

      // ---- build PV A-frags (T12) and accumulate O += P @ V ----
      // permlane32_swap(x, y): x' = {x.lo, y.lo}, y' = {x.hi, y.hi}:
      //  hi=0 lane: x' = own x (keys base+0,1), y' = partner's x (keys base+4,5)
      //  hi=1 lane: x' = partner's y (keys base+8,9), y' = own y (keys base+12,13)
#pragma unroll
      for (int cl = 0; cl < 2; ++cl) {
        auto r0 = __builtin_amdgcn_permlane32_swap(W[4 * cl],     W[4 * cl + 2], false, false);
        auto r1 = __builtin_amdgcn_permlane32_swap(W[4 * cl + 1], W[4 * cl + 3], false, false);
        union { unsigned u[4]; bf16x8 v; } pa;
        pa.u[0] = r0[0]; pa.u[1] = r1[0]; pa.u[2] = r0[1]; pa.u[3] = r1[1];
        __builtin_amdgcn_s_setprio(1);
#pragma unroll
        for (int dblk = 0; dblk < 2; ++dblk) {
          bf16x8 vb = *(const bf16x8*)(Vbase + dblk * 4096 + obase[2 * kb + cl]);
          accO[dblk] = __builtin_amdgcn_mfma_f32_32x32x16_bf16(pa.v, vb, accO[dblk], 0, 0, 0);
        }
        __builtin_amdgcn_s_setprio(0);
      }
    }

    asm volatile("s_waitcnt vmcnt(0)" ::: "memory");
    __syncthreads();
  }

  // ---- epilogue: O[qrow][dk] / l[qrow]; inv broadcast lane->reg layout ----
  const float inv = 1.f / l;
  const int b = bh >> 4, h = bh & 15;
  const int abase = hi * 16;
#pragma unroll
  for (int r = 0; r < 16; ++r) {
    const int rho = (r & 3) + 8 * (r >> 2) + 4 * hi;
    const float invr = __int_as_float(
        __builtin_amdgcn_ds_bpermute(abase + ((r & 3) + 8 * (r >> 2)) * 4, __float_as_int(inv)));
    const int token = b * SS + q0 + w * 32 + rho;
#pragma unroll
    for (int dblk = 0; dblk < 2; ++dblk)
      Ctx[(size_t)token * DM + h * DKH + 32 * dblk + lr32] = f2bf(accO[dblk][r] * invr);
  }
}

// ---------------------------------------------------------------------------
// Launch
// ---------------------------------------------------------------------------
extern "C" void kernel_launch(void* const* d_in, const int* in_sizes, int n_in,
                              void* d_out, int out_size, void* d_ws, size_t ws_size,
                              hipStream_t stream) {
  const float* q  = (const float*)d_in[0];
  const float* k  = (const float*)d_in[1];
  const float* v  = (const float*)d_in[2];
  const float* wq = (const float*)d_in[3];
  const float* bq = (const float*)d_in[4];
  const float* wk = (const float*)d_in[5];
  const float* bk = (const float*)d_in[6];
  const float* wv = (const float*)d_in[7];
  const float* bv = (const float*)d_in[8];
  const float* wo = (const float*)d_in[9];
  const float* bo = (const float*)d_in[10];

  // Workspace layout (120 MB). VT aliases XQ (dead after the Q projection).
  char* ws = (char*)d_ws;
  const size_t ACT = (size_t)MT * DM * 2;   // 16 MB
  const size_t WSZ = (size_t)DM * DM * 2;   //  2 MB
  unsigned short* XQ  = (unsigned short*)(ws);
  unsigned short* XK  = (unsigned short*)(ws + ACT);
  unsigned short* XV  = (unsigned short*)(ws + 2 * ACT);
  unsigned short* WQb = (unsigned short*)(ws + 3 * ACT);
  unsigned short* WKb = (unsigned short*)(ws + 3 * ACT + WSZ);
  unsigned short* WVb = (unsigned short*)(ws + 3 * ACT + 2 * WSZ);
  unsigned short* WOb = (unsigned short*)(ws + 3 * ACT + 3 * WSZ);
  unsigned short* QH  = (unsigned short*)(ws + 3 * ACT + 4 * WSZ);
  unsigned short* KH  = (unsigned short*)(ws + 4 * ACT + 4 * WSZ);
  unsigned short* VH  = (unsigned short*)(ws + 5 * ACT + 4 * WSZ);
  unsigned short* CTX = (unsigned short*)(ws + 6 * ACT + 4 * WSZ);
  unsigned short* VT  = XQ;   // reuse

  cvt_all<<<dim3(2048), dim3(256), 0, stream>>>(q, k, v, wq, wk, wv, wo,
                                                XQ, XK, XV, WQb, WKb, WVb, WOb);

  const dim3 gg(DM / 128, MT / 128, 1);  // (8, 64)
  gemm_bt<0><<<gg, 256, 0, stream>>>(XQ, WQb, bq, QSCALE, QH);
  gemm_bt<0><<<gg, 256, 0, stream>>>(XK, WKb, bk, 1.0f, KH);
  gemm_bt<0><<<gg, 256, 0, stream>>>(XV, WVb, bv, 1.0f, VH);

  transposeV<<<dim3(SS / 64, BB * NH), 256, 0, stream>>>(VH, VT);

  attn<<<dim3(SS / 256, BB * NH), 512, 0, stream>>>(QH, KH, VT, CTX);

  gemm_bt<1><<<gg, 256, 0, stream>>>(CTX, WOb, bo, 1.0f, (float*)d_out);
}